// Round 1
// 577.065 us; speedup vs baseline: 1.0938x; 1.0938x over previous
//
#include <hip/hip_runtime.h>

// Attention_14353780703904: B=8, S=2048, D=1024, fp32 in/out.
//   proj = x @ W^T + b ; scores = x @ proj^T ; weights = softmax(scores) ;
//   ctx = weights @ x.  Outputs: [ctx (B*S*D) | weights (B*S*S)] fp32.
//
// R5: counted-vmcnt deep pipeline (T3+T4), replacing the 2-barrier-per-K-step
// structure whose measured ceiling is ~36% MfmaUtil (R4: 34%).
//  - 512 threads / 8 waves, block tile 256x256, BK=32, wave tile 64x128.
//  - 3 LDS stage buffers (DUAL: 3x48KB=144KB dynamic), 1 block/CU, 2 waves/SIMD.
//  - main loop: s_waitcnt vmcnt(6) (stage k+1 stays IN FLIGHT across the raw
//    s_barrier), issue stage k+2, ds_read frags, setprio(1) MFMA setprio(0).
//    vmcnt only drains to 0 on the final iteration.
//  - numerics identical to R4 (same split-f16 DUAL, same MFMA, same epilogue).

typedef _Float16 f16;
typedef _Float16 f16x8 __attribute__((ext_vector_type(8)));
typedef _Float16 f16x4 __attribute__((ext_vector_type(4)));
typedef float f32x4 __attribute__((ext_vector_type(4)));
typedef unsigned int u32;

#define AS1 __attribute__((address_space(1)))
#define AS3 __attribute__((address_space(3)))

static constexpr int Bb = 8, Ss = 2048, Dd = 1024;

// ---------------- split cast: fp32 -> (hi, lo) fp16 ----------------
__global__ __launch_bounds__(256) void split_cast_k(
    const float* __restrict__ in, f16* __restrict__ hi, f16* __restrict__ lo,
    size_t n4) {
  size_t i = (size_t)blockIdx.x * 256 + threadIdx.x;
  if (i >= n4) return;
  float4 v = ((const float4*)in)[i];
  f16x4 h, l;
  h[0] = (f16)v.x; l[0] = (f16)(v.x - (float)h[0]);
  h[1] = (f16)v.y; l[1] = (f16)(v.y - (float)h[1]);
  h[2] = (f16)v.z; l[2] = (f16)(v.z - (float)h[2]);
  h[3] = (f16)v.w; l[3] = (f16)(v.w - (float)h[3]);
  ((f16x4*)hi)[i] = h;
  ((f16x4*)lo)[i] = l;
}

// ---------------- plain cast: fp32 -> fp16 ----------------
__global__ __launch_bounds__(256) void cast_k(const float* __restrict__ in,
                                              f16* __restrict__ out,
                                              size_t n4) {
  size_t i = (size_t)blockIdx.x * 256 + threadIdx.x;
  if (i >= n4) return;
  float4 v = ((const float4*)in)[i];
  f16x4 h;
  h[0] = (f16)v.x; h[1] = (f16)v.y; h[2] = (f16)v.z; h[3] = (f16)v.w;
  ((f16x4*)out)[i] = h;
}

// ---------------- transpose+cast: x[b][s][d] fp32 -> xT[b][d][s] fp16 ------
__global__ __launch_bounds__(256) void transpose_cast_k(
    const float* __restrict__ x, f16* __restrict__ xT) {
  __shared__ f16 tile[32][33];
  const int b = blockIdx.z;
  const int s0 = blockIdx.x * 32, d0 = blockIdx.y * 32;
  const int tx = threadIdx.x & 31, ty = threadIdx.x >> 5;  // 32 x 8
  const float* xb = x + (size_t)b * Ss * Dd;
#pragma unroll
  for (int r = 0; r < 32; r += 8)
    tile[ty + r][tx] = (f16)xb[(size_t)(s0 + ty + r) * Dd + d0 + tx];
  __syncthreads();
  f16* xTb = xT + (size_t)b * Dd * Ss;
#pragma unroll
  for (int r = 0; r < 32; r += 8)
    xTb[(size_t)(d0 + ty + r) * Ss + s0 + tx] = tile[tx][ty + r];
}

// ---------------- stage panels in MFMA-fragment order ----------------------
// Panel p = 16 rows x 32 k = 1024B, stored so lane l holds element
// (row p*16+(l&15), k (l>>4)*8 .. +7) at panel_base + l*16.  Fragment
// reads are then ds_read_b128 at base+lane*16: zero bank conflicts
// (verified R2). Global side: 16 rows x 64B per instruction.
// 8 waves, PPW panels per wave -> 16 panels per region (256 rows/cols).
template <int PPW>
__device__ __forceinline__ void stage_tile(const f16* __restrict__ g,
                                           size_t ld, f16* lds, int wave,
                                           int lane) {
#pragma unroll
  for (int c = 0; c < PPW; ++c) {
    int panel = wave * PPW + c;
    const f16* gp =
        g + (size_t)(panel * 16 + (lane & 15)) * ld + (lane >> 4) * 8;
    AS3 u32* lp = (AS3 u32*)(lds + panel * 512);
    __builtin_amdgcn_global_load_lds((const AS1 u32*)gp, lp, 16, 0, 0);
  }
}

// ---------------- batched C = A * B^T (+bias) ------------------------------
// DUAL_A: C = (A0 + A1) * B0^T (two A segments share one staged B tile).
// A: [M][K] f16, B: [N][K] f16, C fp32 [M][ldc] or f16 (OUT_F16).
// Block tile 256(M) x 256(N), BK=32; 8 waves 4x2, wave tile 64x128.
// Triple-buffered LDS, counted vmcnt (never 0 in main loop), one raw
// s_barrier per k-iter. grid: (N/256, M/256, batch), 512 threads.
template <bool DUAL_A, bool OUT_F16>
__global__ __launch_bounds__(512, 2) void gemm_bt(
    const f16* __restrict__ A0, const f16* __restrict__ A1,
    const f16* __restrict__ B0, float* __restrict__ C, f16* __restrict__ Ch,
    const float* __restrict__ bias, int K, size_t ldc, size_t sA, size_t sB,
    size_t sC) {
  extern __shared__ f16 smem[];
  const int tid = threadIdx.x;
  const int wave = tid >> 6, lane = tid & 63;
  const size_t tn = (size_t)blockIdx.x * 256;
  const size_t tm = (size_t)blockIdx.y * 256;
  const int b = blockIdx.z;

  constexpr int STAGE = (DUAL_A ? 3 : 2) * 8192;  // f16 elems per stage buffer
  constexpr int BOFF = DUAL_A ? 16384 : 8192;     // B region offset in stage

  const f16* Ah = A0 + (size_t)b * sA + tm * (size_t)K;
  const f16* Al = DUAL_A ? (A1 + (size_t)b * sA + tm * (size_t)K) : nullptr;
  const f16* Bp = B0 + (size_t)b * sB + tn * (size_t)K;

  const int wr = wave >> 1, wc = wave & 1;  // 4 x 2 wave grid
  const int pA = wr * 4;  // A panels [pA, pA+4)   (64 rows)
  const int pB = wc * 8;  // B panels [pB, pB+8)   (128 cols)

  f16* b0 = smem;              // compute buffer (stage it)
  f16* b1 = smem + STAGE;      // stage it+1 (in flight across barrier)
  f16* b2 = smem + 2 * STAGE;  // stage it+2 target

  auto stage_all = [&](int k, f16* buf) {
    stage_tile<2>(Ah + k, K, buf, wave, lane);
    if constexpr (DUAL_A) stage_tile<2>(Al + k, K, buf + 8192, wave, lane);
    stage_tile<2>(Bp + k, K, buf + BOFF, wave, lane);
  };  // 6 (DUAL) / 4 global_load_lds per wave per stage

  f32x4 acc[4][8] = {};

  const int nIter = K / 32;
  stage_all(0, b0);
  stage_all(32, b1);
  for (int it = 0; it < nIter; ++it) {
    // Wait for stage `it` only; stage `it+1` (6/4 loads) stays in flight.
    if (it < nIter - 1) {
      if constexpr (DUAL_A)
        asm volatile("s_waitcnt vmcnt(6)" ::: "memory");
      else
        asm volatile("s_waitcnt vmcnt(4)" ::: "memory");
    } else {
      asm volatile("s_waitcnt vmcnt(0)" ::: "memory");
    }
    __builtin_amdgcn_s_barrier();
    asm volatile("" ::: "memory");
    // b2 held stage it-1: all waves finished reading it before this barrier
    // (their ds_reads completed before their it-1 MFMAs issued). Safe to fill.
    if (it + 2 < nIter) stage_all((it + 2) * 32, b2);

    f16x8 ah[4], al[4];
#pragma unroll
    for (int i = 0; i < 4; ++i) {
      ah[i] = *(const f16x8*)&b0[(pA + i) * 512 + lane * 8];
      if constexpr (DUAL_A)
        al[i] = *(const f16x8*)&b0[8192 + (pA + i) * 512 + lane * 8];
    }
    __builtin_amdgcn_s_setprio(1);
#pragma unroll
    for (int j = 0; j < 8; ++j) {
      f16x8 bf = *(const f16x8*)&b0[BOFF + (pB + j) * 512 + lane * 8];
#pragma unroll
      for (int i = 0; i < 4; ++i) {
        acc[i][j] =
            __builtin_amdgcn_mfma_f32_16x16x32_f16(ah[i], bf, acc[i][j], 0, 0, 0);
        if constexpr (DUAL_A)
          acc[i][j] = __builtin_amdgcn_mfma_f32_16x16x32_f16(al[i], bf,
                                                             acc[i][j], 0, 0, 0);
      }
    }
    __builtin_amdgcn_s_setprio(0);
    f16* t = b0; b0 = b1; b1 = b2; b2 = t;
  }

  // epilogue: C/D layout col = lane&15, row = (lane>>4)*4 + reg
  const int wm = wr * 64, wn = wc * 128;
#pragma unroll
  for (int i = 0; i < 4; ++i) {
    size_t row0 = tm + wm + i * 16 + ((lane >> 4) << 2);
#pragma unroll
    for (int j = 0; j < 8; ++j) {
      size_t col = tn + wn + j * 16 + (lane & 15);
      float bj = bias ? bias[col] : 0.f;
#pragma unroll
      for (int r = 0; r < 4; ++r) {
        float v = acc[i][j][r] + bj;
        size_t off = (size_t)b * sC + (row0 + r) * ldc + col;
        if constexpr (OUT_F16)
          Ch[off] = (f16)v;
        else
          C[off] = v;
      }
    }
  }
}

// ---------------- row softmax (2048 cols), in-place fp32 + f16 copy --------
__global__ __launch_bounds__(256) void softmax_k(float* __restrict__ sc,
                                                 f16* __restrict__ wh) {
  const size_t row = blockIdx.x;
  float* p = sc + row * 2048;
  f16* w = wh + row * 2048;
  const int t = threadIdx.x;
  float4 v0 = ((const float4*)p)[t];
  float4 v1 = ((const float4*)p)[256 + t];
  float m = fmaxf(fmaxf(fmaxf(v0.x, v0.y), fmaxf(v0.z, v0.w)),
                  fmaxf(fmaxf(v1.x, v1.y), fmaxf(v1.z, v1.w)));
#pragma unroll
  for (int o = 32; o; o >>= 1) m = fmaxf(m, __shfl_xor(m, o, 64));
  __shared__ float red[4];
  if ((t & 63) == 0) red[t >> 6] = m;
  __syncthreads();
  m = fmaxf(fmaxf(red[0], red[1]), fmaxf(red[2], red[3]));
  v0.x = __expf(v0.x - m);
  v0.y = __expf(v0.y - m);
  v0.z = __expf(v0.z - m);
  v0.w = __expf(v0.w - m);
  v1.x = __expf(v1.x - m);
  v1.y = __expf(v1.y - m);
  v1.z = __expf(v1.z - m);
  v1.w = __expf(v1.w - m);
  float s = v0.x + v0.y + v0.z + v0.w + v1.x + v1.y + v1.z + v1.w;
#pragma unroll
  for (int o = 32; o; o >>= 1) s += __shfl_xor(s, o, 64);
  __shared__ float red2[4];
  if ((t & 63) == 0) red2[t >> 6] = s;
  __syncthreads();
  s = red2[0] + red2[1] + red2[2] + red2[3];
  float inv = 1.0f / s;
  v0.x *= inv; v0.y *= inv; v0.z *= inv; v0.w *= inv;
  v1.x *= inv; v1.y *= inv; v1.z *= inv; v1.w *= inv;
  ((float4*)p)[t] = v0;
  ((float4*)p)[256 + t] = v1;
  f16x4 h0, h1;
  h0[0] = (f16)v0.x; h0[1] = (f16)v0.y; h0[2] = (f16)v0.z; h0[3] = (f16)v0.w;
  h1[0] = (f16)v1.x; h1[1] = (f16)v1.y; h1[2] = (f16)v1.z; h1[3] = (f16)v1.w;
  ((f16x4*)w)[t] = h0;
  ((f16x4*)w)[256 + t] = h1;
}

extern "C" void kernel_launch(void* const* d_in, const int* in_sizes, int n_in,
                              void* d_out, int out_size, void* d_ws,
                              size_t ws_size, hipStream_t stream) {
  (void)in_sizes; (void)n_in; (void)out_size; (void)ws_size;
  const float* x = (const float*)d_in[0];     // [B,S,D]
  const float* W = (const float*)d_in[1];     // [D,D]
  const float* bias = (const float*)d_in[2];  // [D]
  float* ctx = (float*)d_out;                            // [B,S,D]
  float* scores = (float*)d_out + (size_t)Bb * Ss * Dd;  // [B,S,S]

  const size_t nBSD = (size_t)Bb * Ss * Dd;  // 16,777,216
  const size_t nDD = (size_t)Dd * Dd;        // 1,048,576

  f16* p = (f16*)d_ws;
  f16* x_hi = p; p += nBSD;
  f16* x_lo = p; p += nBSD;
  f16* xT   = p; p += nBSD;
  f16* W_hi = p; p += nDD;
  f16* p_hi = p; p += nBSD;
  // attnw [B,S,S] f16 aliases x_hi+x_lo (dead after GEMM2; exact size match)
  f16* attnw = x_hi;
  // total ws use: (4*nBSD + nDD)*2 bytes = ~136 MB

  // one-time opt-in for >64KB dynamic LDS (host-side attr, not captured)
  static bool attr_done = false;
  if (!attr_done) {
    hipFuncSetAttribute(reinterpret_cast<const void*>(&gemm_bt<true, true>),
                        hipFuncAttributeMaxDynamicSharedMemorySize, 147456);
    hipFuncSetAttribute(reinterpret_cast<const void*>(&gemm_bt<true, false>),
                        hipFuncAttributeMaxDynamicSharedMemorySize, 147456);
    hipFuncSetAttribute(reinterpret_cast<const void*>(&gemm_bt<false, false>),
                        hipFuncAttributeMaxDynamicSharedMemorySize, 147456);
    attr_done = true;
  }
  constexpr unsigned LDS_DUAL = 3u * 24576u * 2u;    // 147456 B
  constexpr unsigned LDS_SINGLE = 3u * 16384u * 2u;  // 98304 B

  // casts
  split_cast_k<<<(unsigned)(nBSD / 4 / 256), 256, 0, stream>>>(x, x_hi, x_lo,
                                                               nBSD / 4);
  cast_k<<<(unsigned)(nDD / 4 / 256), 256, 0, stream>>>(W, W_hi, nDD / 4);
  transpose_cast_k<<<dim3(Ss / 32, Dd / 32, Bb), 256, 0, stream>>>(x, xT);

  // GEMM1: proj = (x_hi + x_lo) @ W_hi^T + b -> f16   M=B*S, N=D, K=D
  gemm_bt<true, true>
      <<<dim3(Dd / 256, (Bb * Ss) / 256, 1), 512, LDS_DUAL, stream>>>(
          x_hi, x_lo, W_hi, nullptr, p_hi, bias, Dd, (size_t)Dd, 0, 0, 0);

  // GEMM2: scores[b] = (x_hi + x_lo)[b] @ p_hi[b]^T -> fp32   M=N=S, K=D
  gemm_bt<true, false>
      <<<dim3(Ss / 256, Ss / 256, Bb), 512, LDS_DUAL, stream>>>(
          x_hi, x_lo, p_hi, scores, nullptr, nullptr, Dd, (size_t)Ss,
          (size_t)Ss * Dd, (size_t)Ss * Dd, (size_t)Ss * Ss);

  // softmax rows, in-place fp32 + f16 copy (into attnw, aliasing dead x_hi)
  softmax_k<<<Bb * Ss, 256, 0, stream>>>(scores, attnw);

  // GEMM4: ctx[b] = attnw[b] @ xT[b]  (B = xT [D][S])   M=S, N=D, K=S
  gemm_bt<false, false>
      <<<dim3(Dd / 256, Ss / 256, Bb), 512, LDS_SINGLE, stream>>>(
          attnw, nullptr, xT, ctx, nullptr, nullptr, Ss, (size_t)Dd,
          (size_t)Ss * Ss, (size_t)Dd * Ss, (size_t)Ss * Dd);
}

// Round 2
// 570.948 us; speedup vs baseline: 1.1056x; 1.0107x over previous
//
#include <hip/hip_runtime.h>

// Attention_14353780703904: B=8, S=2048, D=1024, fp32 in/out.
//   proj = x @ W^T + b ; scores = x @ proj^T ; weights = softmax(scores) ;
//   ctx = weights @ x.  Outputs: [ctx (B*S*D) | weights (B*S*S)] fp32.
//
// R6: template-style 2-phase K-iter (T3) on top of R5's counted-vmcnt triple
// buffer. Per iter: phase A {reads ah/bf03/al, A-gloads, barrier, pure MFMA
// cluster j=0..3}, phase B {reads bf47, B-gloads, barrier, pure MFMA cluster
// j=4..7}. Pure-register MFMA clusters give setprio(1) real role diversity
// (T5 is null without phase-split, m190/m218b). hi-cluster then lo-cluster
// separates dual dependent MFMA pairs by 16 issues; per-acc-element op order
// unchanged -> bitwise-identical numerics to R5.

typedef _Float16 f16;
typedef _Float16 f16x8 __attribute__((ext_vector_type(8)));
typedef _Float16 f16x4 __attribute__((ext_vector_type(4)));
typedef float f32x4 __attribute__((ext_vector_type(4)));
typedef unsigned int u32;

#define AS1 __attribute__((address_space(1)))
#define AS3 __attribute__((address_space(3)))

#define FENCE() asm volatile("" ::: "memory")
#define BARRIER()                  \
  do {                             \
    FENCE();                       \
    __builtin_amdgcn_s_barrier();  \
    FENCE();                       \
  } while (0)

static constexpr int Bb = 8, Ss = 2048, Dd = 1024;

// ---------------- split cast: fp32 -> (hi, lo) fp16 ----------------
__global__ __launch_bounds__(256) void split_cast_k(
    const float* __restrict__ in, f16* __restrict__ hi, f16* __restrict__ lo,
    size_t n4) {
  size_t i = (size_t)blockIdx.x * 256 + threadIdx.x;
  if (i >= n4) return;
  float4 v = ((const float4*)in)[i];
  f16x4 h, l;
  h[0] = (f16)v.x; l[0] = (f16)(v.x - (float)h[0]);
  h[1] = (f16)v.y; l[1] = (f16)(v.y - (float)h[1]);
  h[2] = (f16)v.z; l[2] = (f16)(v.z - (float)h[2]);
  h[3] = (f16)v.w; l[3] = (f16)(v.w - (float)h[3]);
  ((f16x4*)hi)[i] = h;
  ((f16x4*)lo)[i] = l;
}

// ---------------- plain cast: fp32 -> fp16 ----------------
__global__ __launch_bounds__(256) void cast_k(const float* __restrict__ in,
                                              f16* __restrict__ out,
                                              size_t n4) {
  size_t i = (size_t)blockIdx.x * 256 + threadIdx.x;
  if (i >= n4) return;
  float4 v = ((const float4*)in)[i];
  f16x4 h;
  h[0] = (f16)v.x; h[1] = (f16)v.y; h[2] = (f16)v.z; h[3] = (f16)v.w;
  ((f16x4*)out)[i] = h;
}

// ---------------- transpose+cast: x[b][s][d] fp32 -> xT[b][d][s] fp16 ------
__global__ __launch_bounds__(256) void transpose_cast_k(
    const float* __restrict__ x, f16* __restrict__ xT) {
  __shared__ f16 tile[32][33];
  const int b = blockIdx.z;
  const int s0 = blockIdx.x * 32, d0 = blockIdx.y * 32;
  const int tx = threadIdx.x & 31, ty = threadIdx.x >> 5;  // 32 x 8
  const float* xb = x + (size_t)b * Ss * Dd;
#pragma unroll
  for (int r = 0; r < 32; r += 8)
    tile[ty + r][tx] = (f16)xb[(size_t)(s0 + ty + r) * Dd + d0 + tx];
  __syncthreads();
  f16* xTb = xT + (size_t)b * Dd * Ss;
#pragma unroll
  for (int r = 0; r < 32; r += 8)
    xTb[(size_t)(d0 + ty + r) * Ss + s0 + tx] = tile[tx][ty + r];
}

// ---------------- stage panels in MFMA-fragment order ----------------------
// Panel p = 16 rows x 32 k = 1024B, stored so lane l holds element
// (row p*16+(l&15), k (l>>4)*8 .. +7) at panel_base + l*16.  Fragment
// reads are then ds_read_b128 at base+lane*16: zero bank conflicts
// (verified R2). Global side: 16 rows x 64B per instruction.
// 8 waves, PPW panels per wave -> 16 panels per region (256 rows/cols).
template <int PPW>
__device__ __forceinline__ void stage_tile(const f16* __restrict__ g,
                                           size_t ld, f16* lds, int wave,
                                           int lane) {
#pragma unroll
  for (int c = 0; c < PPW; ++c) {
    int panel = wave * PPW + c;
    const f16* gp =
        g + (size_t)(panel * 16 + (lane & 15)) * ld + (lane >> 4) * 8;
    AS3 u32* lp = (AS3 u32*)(lds + panel * 512);
    __builtin_amdgcn_global_load_lds((const AS1 u32*)gp, lp, 16, 0, 0);
  }
}

// ---------------- batched C = A * B^T (+bias) ------------------------------
// DUAL_A: C = (A0 + A1) * B0^T (two A segments share one staged B tile).
// A: [M][K] f16, B: [N][K] f16, C fp32 [M][ldc] or f16 (OUT_F16).
// Block tile 256(M) x 256(N), BK=32; 8 waves 4x2, wave tile 64x128.
// Triple-buffered LDS, counted vmcnt (never 0 in main loop), 2 phases per
// k-iter with pure-register MFMA clusters. grid: (N/256, M/256, batch).
template <bool DUAL_A, bool OUT_F16>
__global__ __launch_bounds__(512, 2) void gemm_bt(
    const f16* __restrict__ A0, const f16* __restrict__ A1,
    const f16* __restrict__ B0, float* __restrict__ C, f16* __restrict__ Ch,
    const float* __restrict__ bias, int K, size_t ldc, size_t sA, size_t sB,
    size_t sC) {
  extern __shared__ f16 smem[];
  const int tid = threadIdx.x;
  const int wave = tid >> 6, lane = tid & 63;
  const size_t tn = (size_t)blockIdx.x * 256;
  const size_t tm = (size_t)blockIdx.y * 256;
  const int b = blockIdx.z;

  constexpr int STAGE = (DUAL_A ? 3 : 2) * 8192;  // f16 elems per stage buffer
  constexpr int BOFF = DUAL_A ? 16384 : 8192;     // B region offset in stage

  const f16* Ah = A0 + (size_t)b * sA + tm * (size_t)K;
  const f16* Al = DUAL_A ? (A1 + (size_t)b * sA + tm * (size_t)K) : nullptr;
  const f16* Bp = B0 + (size_t)b * sB + tn * (size_t)K;

  const int wr = wave >> 1, wc = wave & 1;  // 4 x 2 wave grid
  const int pA = wr * 4;  // A panels [pA, pA+4)   (64 rows)
  const int pB = wc * 8;  // B panels [pB, pB+8)   (128 cols)

  f16* b0 = smem;              // compute buffer (stage it)
  f16* b1 = smem + STAGE;      // stage it+1 (in flight across barrier)
  f16* b2 = smem + 2 * STAGE;  // stage it+2 target

  auto stageA = [&](int k, f16* buf) {  // A region: 4 (DUAL) / 2 gloads
    stage_tile<2>(Ah + k, K, buf, wave, lane);
    if constexpr (DUAL_A) stage_tile<2>(Al + k, K, buf + 8192, wave, lane);
  };
  auto stageB = [&](int k, f16* buf) {  // B region: 2 gloads
    stage_tile<2>(Bp + k, K, buf + BOFF, wave, lane);
  };

  f32x4 acc[4][8] = {};

  const int nIter = K / 32;
  stageA(0, b0); stageB(0, b0);
  stageA(32, b1); stageB(32, b1);
  for (int it = 0; it < nIter; ++it) {
    // Validate stage `it`: own 6 (DUAL) / 4 loads of stage it+1 stay in
    // flight; barrier publishes completion of ALL waves' stage-it loads.
    if (it < nIter - 1) {
      if constexpr (DUAL_A)
        asm volatile("s_waitcnt vmcnt(6)" ::: "memory");
      else
        asm volatile("s_waitcnt vmcnt(4)" ::: "memory");
    } else {
      asm volatile("s_waitcnt vmcnt(0)" ::: "memory");
    }
    BARRIER();  // also closes prev iter's phase-B cluster: b2 free to fill

    // ---------------- phase A: reads + A-gloads, cluster j=0..3 ----------
    f16x8 ah[4], al[4], bf[4];
#pragma unroll
    for (int i = 0; i < 4; ++i)
      ah[i] = *(const f16x8*)&b0[(pA + i) * 512 + lane * 8];
#pragma unroll
    for (int j = 0; j < 4; ++j)
      bf[j] = *(const f16x8*)&b0[BOFF + (pB + j) * 512 + lane * 8];
    if constexpr (DUAL_A) {
#pragma unroll
      for (int i = 0; i < 4; ++i)
        al[i] = *(const f16x8*)&b0[8192 + (pA + i) * 512 + lane * 8];
    }
    if (it + 2 < nIter) stageA((it + 2) * 32, b2);
    BARRIER();
    __builtin_amdgcn_s_setprio(1);
#pragma unroll
    for (int j = 0; j < 4; ++j)
#pragma unroll
      for (int i = 0; i < 4; ++i)
        acc[i][j] =
            __builtin_amdgcn_mfma_f32_16x16x32_f16(ah[i], bf[j], acc[i][j], 0, 0, 0);
    if constexpr (DUAL_A) {
#pragma unroll
      for (int j = 0; j < 4; ++j)
#pragma unroll
        for (int i = 0; i < 4; ++i)
          acc[i][j] = __builtin_amdgcn_mfma_f32_16x16x32_f16(al[i], bf[j],
                                                             acc[i][j], 0, 0, 0);
    }
    __builtin_amdgcn_s_setprio(0);

    // ---------------- phase B: reads + B-gloads, cluster j=4..7 ----------
    BARRIER();
    f16x8 bg[4];
#pragma unroll
    for (int j = 0; j < 4; ++j)
      bg[j] = *(const f16x8*)&b0[BOFF + (pB + 4 + j) * 512 + lane * 8];
    if (it + 2 < nIter) stageB((it + 2) * 32, b2);
    BARRIER();
    __builtin_amdgcn_s_setprio(1);
#pragma unroll
    for (int j = 0; j < 4; ++j)
#pragma unroll
      for (int i = 0; i < 4; ++i)
        acc[i][4 + j] = __builtin_amdgcn_mfma_f32_16x16x32_f16(
            ah[i], bg[j], acc[i][4 + j], 0, 0, 0);
    if constexpr (DUAL_A) {
#pragma unroll
      for (int j = 0; j < 4; ++j)
#pragma unroll
        for (int i = 0; i < 4; ++i)
          acc[i][4 + j] = __builtin_amdgcn_mfma_f32_16x16x32_f16(
              al[i], bg[j], acc[i][4 + j], 0, 0, 0);
    }
    __builtin_amdgcn_s_setprio(0);

    f16* t = b0; b0 = b1; b1 = b2; b2 = t;
  }

  // epilogue: C/D layout col = lane&15, row = (lane>>4)*4 + reg
  const int wm = wr * 64, wn = wc * 128;
#pragma unroll
  for (int i = 0; i < 4; ++i) {
    size_t row0 = tm + wm + i * 16 + ((lane >> 4) << 2);
#pragma unroll
    for (int j = 0; j < 8; ++j) {
      size_t col = tn + wn + j * 16 + (lane & 15);
      float bj = bias ? bias[col] : 0.f;
#pragma unroll
      for (int r = 0; r < 4; ++r) {
        float v = acc[i][j][r] + bj;
        size_t off = (size_t)b * sC + (row0 + r) * ldc + col;
        if constexpr (OUT_F16)
          Ch[off] = (f16)v;
        else
          C[off] = v;
      }
    }
  }
}

// ---------------- row softmax (2048 cols), in-place fp32 + f16 copy --------
__global__ __launch_bounds__(256) void softmax_k(float* __restrict__ sc,
                                                 f16* __restrict__ wh) {
  const size_t row = blockIdx.x;
  float* p = sc + row * 2048;
  f16* w = wh + row * 2048;
  const int t = threadIdx.x;
  float4 v0 = ((const float4*)p)[t];
  float4 v1 = ((const float4*)p)[256 + t];
  float m = fmaxf(fmaxf(fmaxf(v0.x, v0.y), fmaxf(v0.z, v0.w)),
                  fmaxf(fmaxf(v1.x, v1.y), fmaxf(v1.z, v1.w)));
#pragma unroll
  for (int o = 32; o; o >>= 1) m = fmaxf(m, __shfl_xor(m, o, 64));
  __shared__ float red[4];
  if ((t & 63) == 0) red[t >> 6] = m;
  __syncthreads();
  m = fmaxf(fmaxf(red[0], red[1]), fmaxf(red[2], red[3]));
  v0.x = __expf(v0.x - m);
  v0.y = __expf(v0.y - m);
  v0.z = __expf(v0.z - m);
  v0.w = __expf(v0.w - m);
  v1.x = __expf(v1.x - m);
  v1.y = __expf(v1.y - m);
  v1.z = __expf(v1.z - m);
  v1.w = __expf(v1.w - m);
  float s = v0.x + v0.y + v0.z + v0.w + v1.x + v1.y + v1.z + v1.w;
#pragma unroll
  for (int o = 32; o; o >>= 1) s += __shfl_xor(s, o, 64);
  __shared__ float red2[4];
  if ((t & 63) == 0) red2[t >> 6] = s;
  __syncthreads();
  s = red2[0] + red2[1] + red2[2] + red2[3];
  float inv = 1.0f / s;
  v0.x *= inv; v0.y *= inv; v0.z *= inv; v0.w *= inv;
  v1.x *= inv; v1.y *= inv; v1.z *= inv; v1.w *= inv;
  ((float4*)p)[t] = v0;
  ((float4*)p)[256 + t] = v1;
  f16x4 h0, h1;
  h0[0] = (f16)v0.x; h0[1] = (f16)v0.y; h0[2] = (f16)v0.z; h0[3] = (f16)v0.w;
  h1[0] = (f16)v1.x; h1[1] = (f16)v1.y; h1[2] = (f16)v1.z; h1[3] = (f16)v1.w;
  ((f16x4*)w)[t] = h0;
  ((f16x4*)w)[256 + t] = h1;
}

extern "C" void kernel_launch(void* const* d_in, const int* in_sizes, int n_in,
                              void* d_out, int out_size, void* d_ws,
                              size_t ws_size, hipStream_t stream) {
  (void)in_sizes; (void)n_in; (void)out_size; (void)ws_size;
  const float* x = (const float*)d_in[0];     // [B,S,D]
  const float* W = (const float*)d_in[1];     // [D,D]
  const float* bias = (const float*)d_in[2];  // [D]
  float* ctx = (float*)d_out;                            // [B,S,D]
  float* scores = (float*)d_out + (size_t)Bb * Ss * Dd;  // [B,S,S]

  const size_t nBSD = (size_t)Bb * Ss * Dd;  // 16,777,216
  const size_t nDD = (size_t)Dd * Dd;        // 1,048,576

  f16* p = (f16*)d_ws;
  f16* x_hi = p; p += nBSD;
  f16* x_lo = p; p += nBSD;
  f16* xT   = p; p += nBSD;
  f16* W_hi = p; p += nDD;
  f16* p_hi = p; p += nBSD;
  // attnw [B,S,S] f16 aliases x_hi+x_lo (dead after GEMM2; exact size match)
  f16* attnw = x_hi;
  // total ws use: (4*nBSD + nDD)*2 bytes = ~136 MB

  // one-time opt-in for >64KB dynamic LDS (host-side attr, not captured)
  static bool attr_done = false;
  if (!attr_done) {
    hipFuncSetAttribute(reinterpret_cast<const void*>(&gemm_bt<true, true>),
                        hipFuncAttributeMaxDynamicSharedMemorySize, 147456);
    hipFuncSetAttribute(reinterpret_cast<const void*>(&gemm_bt<true, false>),
                        hipFuncAttributeMaxDynamicSharedMemorySize, 147456);
    hipFuncSetAttribute(reinterpret_cast<const void*>(&gemm_bt<false, false>),
                        hipFuncAttributeMaxDynamicSharedMemorySize, 147456);
    attr_done = true;
  }
  constexpr unsigned LDS_DUAL = 3u * 24576u * 2u;    // 147456 B
  constexpr unsigned LDS_SINGLE = 3u * 16384u * 2u;  // 98304 B

  // casts
  split_cast_k<<<(unsigned)(nBSD / 4 / 256), 256, 0, stream>>>(x, x_hi, x_lo,
                                                               nBSD / 4);
  cast_k<<<(unsigned)(nDD / 4 / 256), 256, 0, stream>>>(W, W_hi, nDD / 4);
  transpose_cast_k<<<dim3(Ss / 32, Dd / 32, Bb), 256, 0, stream>>>(x, xT);

  // GEMM1: proj = (x_hi + x_lo) @ W_hi^T + b -> f16   M=B*S, N=D, K=D
  gemm_bt<true, true>
      <<<dim3(Dd / 256, (Bb * Ss) / 256, 1), 512, LDS_DUAL, stream>>>(
          x_hi, x_lo, W_hi, nullptr, p_hi, bias, Dd, (size_t)Dd, 0, 0, 0);

  // GEMM2: scores[b] = (x_hi + x_lo)[b] @ p_hi[b]^T -> fp32   M=N=S, K=D
  gemm_bt<true, false>
      <<<dim3(Ss / 256, Ss / 256, Bb), 512, LDS_DUAL, stream>>>(
          x_hi, x_lo, p_hi, scores, nullptr, nullptr, Dd, (size_t)Ss,
          (size_t)Ss * Dd, (size_t)Ss * Dd, (size_t)Ss * Ss);

  // softmax rows, in-place fp32 + f16 copy (into attnw, aliasing dead x_hi)
  softmax_k<<<Bb * Ss, 256, 0, stream>>>(scores, attnw);

  // GEMM4: ctx[b] = attnw[b] @ xT[b]  (B = xT [D][S])   M=S, N=D, K=S
  gemm_bt<false, false>
      <<<dim3(Dd / 256, Ss / 256, Bb), 512, LDS_SINGLE, stream>>>(
          attnw, nullptr, xT, ctx, nullptr, nullptr, Ss, (size_t)Dd,
          (size_t)Ss * Ss, (size_t)Dd * Ss, (size_t)Ss * Dd);
}